// Round 5
// baseline (640.306 us; speedup 1.0000x reference)
//
#include <hip/hip_runtime.h>
#include <hip/hip_bf16.h>

#define CIN   128
#define EMBD  64
#define KC    512
#define SPAT  32768
#define NVOX  131072
#define QSZ   (NVOX * EMBD)      // 8388608
#define DIFF_OFF QSZ
#define IDX_OFF  (QSZ + 1)

// ---------------------------------------------------------------------------
// Prep: embedT[k][o] = embed[o][k], norms[k] = ||e_k||^2
// ---------------------------------------------------------------------------
__global__ __launch_bounds__(64) void vq_prep(const float* __restrict__ embed,
                                              float* __restrict__ embedT,
                                              float* __restrict__ norms) {
  int k = blockIdx.x;   // 512
  int o = threadIdx.x;  // 64
  float e = embed[o * KC + k];
  embedT[k * EMBD + o] = e;
  float s = e * e;
  #pragma unroll
  for (int off = 32; off > 0; off >>= 1) s += __shfl_down(s, off);
  if (o == 0) norms[k] = s;
}

// ---------------------------------------------------------------------------
// Main: lane-pair per voxel (h = lane>>5 owns o-half). Halves register
// pressure (z[32] not z[64]) -> no AGPR spill -> occupancy. Pair-sum via
// __shfl_xor(dot, 32) per code.
// ---------------------------------------------------------------------------
__global__ __launch_bounds__(256, 4) void vq_main(
    const float* __restrict__ x, const float* __restrict__ conv_w,
    const float* __restrict__ conv_b, const float* __restrict__ embedT,
    const float* __restrict__ norms, float* __restrict__ out,
    float* __restrict__ partials) {
  __shared__ float wlds[CIN * EMBD];            // [c][o], 32 KB
  for (int f = threadIdx.x; f < CIN * EMBD; f += 256) {
    int o = f >> 7;          // conv_w is (EMB=64, C=128): conv_w[o*128+c]
    int c = f & (CIN - 1);
    wlds[c * EMBD + o] = conv_w[f];             // one-time staging
  }
  __syncthreads();

  const int tid   = threadIdx.x;
  const int wv    = tid >> 6;                   // wave 0..3
  const int lane  = tid & 63;
  const int h     = lane >> 5;                  // o-half 0/1
  const int vloc  = lane & 31;
  const int n     = blockIdx.x * 128 + wv * 32 + vloc;   // voxel id
  const int b     = n >> 15;
  const int v     = n & (SPAT - 1);
  const int obase = h * 32;

  const float* xp = x + ((size_t)b * CIN) * SPAT + v;

  // z-half = (W x + b)[obase .. obase+31]
  float z[32];
  #pragma unroll
  for (int i = 0; i < 32; ++i) z[i] = conv_b[obase + i];

  #pragma unroll 4
  for (int c = 0; c < CIN; ++c) {
    float xv = xp[(size_t)c * SPAT];            // coalesced (halves merge)
    const float* wr = &wlds[c * EMBD + obase];  // uniform per half-wave
    #pragma unroll
    for (int i = 0; i < 32; ++i) z[i] = fmaf(xv, wr[i], z[i]);
  }

  // argmin_k ( ||e_k||^2 - 2 z.e_k ); pair-sum the half-dots
  float best = 3.4e38f;
  int bi = 0;
  #pragma unroll 2
  for (int k = 0; k < KC; ++k) {
    const float* ek = embedT + k * EMBD + obase;
    float d0 = 0.f, d1 = 0.f, d2 = 0.f, d3 = 0.f;
    #pragma unroll
    for (int q = 0; q < 8; ++q) {
      float4 e4 = *(const float4*)(ek + q * 4);
      d0 = fmaf(z[q * 4 + 0], e4.x, d0);
      d1 = fmaf(z[q * 4 + 1], e4.y, d1);
      d2 = fmaf(z[q * 4 + 2], e4.z, d2);
      d3 = fmaf(z[q * 4 + 3], e4.w, d3);
    }
    float dot = (d0 + d1) + (d2 + d3);
    dot += __shfl_xor(dot, 32);                 // combine halves (both get sum)
    float s = fmaf(-2.f, dot, norms[k]);
    if (s < best) { best = s; bi = k; }         // strict < = first min (jnp)
  }

  // gather chosen code, write quantize (B,EMB,D,H,W), local diff
  const float* eb = embedT + bi * EMBD + obase;
  float* qout = out + ((size_t)b * EMBD + obase) * SPAT + v;
  float diff = 0.f;
  #pragma unroll
  for (int i = 0; i < 32; ++i) {
    float e = eb[i];
    float r = e - z[i];
    diff = fmaf(r, r, diff);
    qout[(size_t)i * SPAT] = e;                 // 2x128B contiguous per wave
  }
  if (h == 0) out[IDX_OFF + n] = (float)bi;

  // block-reduce diff (each thread covered its o-half)
  #pragma unroll
  for (int off = 32; off > 0; off >>= 1) diff += __shfl_down(diff, off);
  __syncthreads();                              // done with wlds; reuse
  if (lane == 0) wlds[wv] = diff;
  __syncthreads();
  if (tid == 0)
    partials[blockIdx.x] = wlds[0] + wlds[1] + wlds[2] + wlds[3];
}

__global__ __launch_bounds__(512) void vq_final(const float* __restrict__ partials,
                                                float* __restrict__ out) {
  __shared__ float tmp[8];
  float s = partials[threadIdx.x] + partials[threadIdx.x + 512];  // 1024 partials
  #pragma unroll
  for (int off = 32; off > 0; off >>= 1) s += __shfl_down(s, off);
  if ((threadIdx.x & 63) == 0) tmp[threadIdx.x >> 6] = s;
  __syncthreads();
  if (threadIdx.x == 0) {
    float t = 0.f;
    #pragma unroll
    for (int i = 0; i < 8; ++i) t += tmp[i];
    out[DIFF_OFF] = t * (1.0f / (float)QSZ);
  }
}

extern "C" void kernel_launch(void* const* d_in, const int* in_sizes, int n_in,
                              void* d_out, int out_size, void* d_ws, size_t ws_size,
                              hipStream_t stream) {
  const float* x      = (const float*)d_in[0];
  const float* conv_w = (const float*)d_in[1];
  const float* conv_b = (const float*)d_in[2];
  const float* embed  = (const float*)d_in[3];
  float* out = (float*)d_out;
  float* ws  = (float*)d_ws;

  float* embedT   = ws;            // 32768 floats (128 KB)
  float* norms    = ws + 32768;    // 512 floats
  float* partials = ws + 33280;    // 1024 floats

  vq_prep<<<KC, EMBD, 0, stream>>>(embed, embedT, norms);
  vq_main<<<NVOX / 128, 256, 0, stream>>>(x, conv_w, conv_b, embedT, norms,
                                          out, partials);
  vq_final<<<1, 512, 0, stream>>>(partials, out);
}